// Round 18
// baseline (391.849 us; speedup 1.0000x reference)
//
#include <hip/hip_runtime.h>
#include <hip/hip_fp16.h>
#include <cstdint>

using f16 = _Float16;
typedef __attribute__((ext_vector_type(8))) _Float16 f16x8;
typedef __attribute__((ext_vector_type(4))) _Float16 f16x4;
typedef __attribute__((ext_vector_type(4))) float f32x4;

#define MFMA16(a, b, c) __builtin_amdgcn_mfma_f32_16x16x32_f16((a), (b), (c), 0, 0, 0)

__device__ __forceinline__ f16x8 ldfrag(const f16* p) { return *(const f16x8*)p; }

// async global->LDS DMA, 16 B per lane; lds dest = wave-uniform base + lane*16
__device__ __forceinline__ void dma16(const f16* g, f16* l) {
  __builtin_amdgcn_global_load_lds(
      (const __attribute__((address_space(1))) void*)g,
      (__attribute__((address_space(3))) void*)l, 16, 0, 0);
}
// explicit per-wave fences (do NOT rely on compiler LDS-DMA modeling)
__device__ __forceinline__ void wait_vm0() {
  asm volatile("s_waitcnt vmcnt(0)" ::: "memory");
}
__device__ __forceinline__ void wait_lgkm0() {
  asm volatile("s_waitcnt lgkmcnt(0)" ::: "memory");
}
__device__ __forceinline__ void wait_vm4() {
  asm volatile("s_waitcnt vmcnt(4)" ::: "memory");
}
__device__ __forceinline__ void wait_vm2() {
  asm volatile("s_waitcnt vmcnt(2)" ::: "memory");
}

// Problem constants: B=8, T=1024, K=128, H=8 -> M = B*H = 64 scrambled batches.
static const int64_t NX = 1048576;   // x elements: 8*1024*128
static const int64_t NW = 655360;    // Wq/Wk elements: 1024*128*5
static const int64_t NV = 131072;    // Wv / Wu elements: 1024*128

// ---------------- K0: split-convert/repack weights and x to fp16 hi/lo -----
__global__ __launch_bounds__(256) void k0_prep(
    const float* __restrict__ x, const float* __restrict__ Wq,
    const float* __restrict__ Wk, const float* __restrict__ Wv,
    const float* __restrict__ Wu,
    f16* __restrict__ xh, f16* __restrict__ xl,
    f16* __restrict__ Wqh, f16* __restrict__ Wql,
    f16* __restrict__ Wkh, f16* __restrict__ Wkl,
    f16* __restrict__ Wvb, f16* __restrict__ Wub) {
  int64_t i = (int64_t)blockIdx.x * 256 + threadIdx.x;  // grid sized exactly
  if (i < NX) {
    const float v = x[i];
    const f16 h = (f16)v;
    xh[i] = h; xl[i] = (f16)(v - (float)h);
  } else if (i < NX + NW) {
    int64_t d = i - NX;
    int j = (int)(d >> 17);
    int rem = (int)(d & 131071);
    int o = rem >> 7, c = rem & 127;
    const float v = Wq[(int64_t)(o * 128 + c) * 5 + j];   // layout [j][o][c]
    const f16 h = (f16)v;
    Wqh[d] = h; Wql[d] = (f16)(v - (float)h);
  } else if (i < NX + 2 * NW) {
    int64_t d = i - NX - NW;
    int j = (int)(d >> 17);
    int rem = (int)(d & 131071);
    int o = rem >> 7, c = rem & 127;
    const float v = Wk[(int64_t)(o * 128 + c) * 5 + j];
    const f16 h = (f16)v;
    Wkh[d] = h; Wkl[d] = (f16)(v - (float)h);
  } else if (i < NX + 2 * NW + NV) {
    int64_t d = i - NX - 2 * NW;
    Wvb[d] = (f16)Wv[d];                                // [o][c]
  } else {
    int64_t d = i - NX - 2 * NW - NV;
    Wub[d] = (f16)Wu[d];                                // [c][o]
  }
}

// ---------------- K1: causal convs, 64 T-rows/block ------------------------
// A-frags hoisted per (j,kk); continuous half-chunk pipelined weight stream.
#define STAGE_QK(DST, PASS, VALEXPR)                                    \
  {                                                                     \
    __syncthreads();                                                    \
    _Pragma("unroll")                                                   \
    for (int nt = 0; nt < 8; ++nt) {                                    \
      const int o = o0 + nt * 16 + lo;                                  \
      const int kcl = (o >> 3) & 63, hh = o & 7;                        \
      _Pragma("unroll")                                                 \
      for (int rtl = 0; rtl < 2; ++rtl) {                               \
        const int rt = (PASS) * 2 + rtl;                                \
        _Pragma("unroll")                                               \
        for (int r = 0; r < 4; ++r) {                                   \
          const int t2l = (rtl * 16 + quad * 4 + r) * 8 + hh;           \
          lds[t2l * 72 + kcl] = (VALEXPR);                              \
        }                                                               \
      }                                                                 \
    }                                                                   \
    __syncthreads();                                                    \
    _Pragma("unroll")                                                   \
    for (int p = 0; p < 8; ++p) {                                       \
      const int idx = p * 256 + tid;                                    \
      const int a = idx >> 3, c8 = (idx & 7) * 8;                       \
      *(f16x8*)(DST + ((int64_t)m * 1024 + t2b + (PASS) * 256 + a) * 128 + \
                half * 64 + c8) = *(const f16x8*)&lds[a * 72 + c8];     \
    }                                                                   \
  }

__global__ __launch_bounds__(256) void k1_conv(
    const f16* __restrict__ xh, const f16* __restrict__ xl,
    const f16* __restrict__ Wqh, const f16* __restrict__ Wql,
    const f16* __restrict__ Wkh, const f16* __restrict__ Wkl,
    const f16* __restrict__ Wvb,
    const float* __restrict__ bq, const float* __restrict__ bk,
    const float* __restrict__ bv,
    f16* __restrict__ q3h, f16* __restrict__ q3l,
    f16* __restrict__ k3h, f16* __restrict__ k3l,
    f16* __restrict__ v3T) {
  __shared__ f16 shm[36384];      // 72.8 KB: [0,18432) wbuf/stage, rest xbuf
  f16* const wbuf = shm;
  f16* const xbuf = shm + 18432;  // 68 rows x 264 f16
  f16* const lds  = shm;          // staging alias
  const int tid = threadIdx.x;
  const int w = tid >> 6, lane = tid & 63;
  const int quad = lane >> 4, lo = lane & 15;
  const int r0 = blockIdx.x * 64;     // rows r0..r0+63 (same b, same m)
  const int bb = r0 >> 10;
  const int m  = r0 >> 7;
  const int t2b = (r0 & 127) * 8;     // 0 or 512
  const int tloc = r0 & 1023;
  const int half = blockIdx.y;        // which 512-channel half
  const int isK = blockIdx.z;         // 0 = Q (+V), 1 = K
  const int o0 = half * 512 + w * 128;

  const f16* Wh = isK ? Wkh : Wqh;
  const f16* Wl = isK ? Wkl : Wql;
  const float* bias = isK ? bk : bq;

  // ---- stage x rows [tloc-4, tloc+64) (clamped at batch start) ----
#pragma unroll
  for (int p = 0; p < 9; ++p) {
    const int u = p * 256 + tid;           // f16x8 unit
    if (u < 2176) {
      const int row = u >> 5, tz = (u >> 4) & 1, c8 = (u & 15) * 8;
      int lt = tloc - 4 + row;
      if (lt < 0) lt = 0;
      const f16* src = (tz ? xl : xh) + ((int64_t)(bb * 1024 + lt)) * 128 + c8;
      *(f16x8*)&xbuf[row * 264 + tz * 128 + c8] = *(const f16x8*)src;
    }
  }
  __syncthreads();

  // per-lane gather offset within a 16n x 128c fragment block
  const int64_t wlane = (int64_t)(lane & 15) * 128 + (lane >> 4) * 8;

  // ---- V pass (Q-blocks only): pointwise tap, hi only; barrier-free ----
  if (!isK) {
    f32x4 av[4][8];
#pragma unroll
    for (int rt = 0; rt < 4; ++rt)
#pragma unroll
      for (int i = 0; i < 8; ++i)
#pragma unroll
        for (int r = 0; r < 4; ++r) av[rt][i][r] = 0.f;

#pragma unroll
    for (int g = 0; g < 4; ++g) {
#pragma unroll
      for (int s = 0; s < 2; ++s) {
        const int64_t vsrc = (int64_t)(o0 + (g * 2 + s) * 16) * 128 + wlane;
#pragma unroll
        for (int kk = 0; kk < 4; ++kk)
          dma16(Wvb + vsrc + kk * 32, wbuf + w * 4096 + s * 2048 + kk * 512);
      }
      wait_vm0();   // own DMA landed
#pragma unroll
      for (int kk = 0; kk < 4; ++kk) {
        f16x8 a[4];
#pragma unroll
        for (int rt = 0; rt < 4; ++rt)
          a[rt] = *(const f16x8*)&xbuf[(rt * 16 + lo + 4) * 264 + kk * 32 +
                                       quad * 8];
#pragma unroll
        for (int s = 0; s < 2; ++s) {
          const f16x8 bv8 = *(const f16x8*)&wbuf[w * 4096 + s * 2048 + kk * 512 +
                                                 quad * 128 + lo * 8];
#pragma unroll
          for (int rt = 0; rt < 4; ++rt)
            av[rt][g * 2 + s] = MFMA16(a[rt], bv8, av[rt][g * 2 + s]);
        }
      }
      wait_lgkm0();  // own ds_reads sampled before next DMA can land
    }
    __syncthreads();  // all waves done with wbuf before cross-wave staging
    // bias + stage v3T via LDS [kcl][t2l] (stride 264), two 256-col passes
#pragma unroll
    for (int pass = 0; pass < 2; ++pass) {
#pragma unroll
      for (int nt = 0; nt < 8; ++nt) {
        const int o = o0 + nt * 16 + lo;
        const float vbv = bv[o];
        const int kcl = (o >> 3) & 63, hh = o & 7;
#pragma unroll
        for (int rtl = 0; rtl < 2; ++rtl)
#pragma unroll
          for (int r = 0; r < 4; ++r) {
            const int t2l = (rtl * 16 + quad * 4 + r) * 8 + hh;
            lds[kcl * 264 + t2l] = (f16)(av[pass * 2 + rtl][nt][r] + vbv);
          }
      }
      __syncthreads();
#pragma unroll
      for (int p = 0; p < 8; ++p) {
        const int idx = p * 256 + tid;
        const int kcl = idx >> 5, t8 = (idx & 31) * 8;
        *(f16x8*)(v3T + ((int64_t)m * 128 + half * 64 + kcl) * 1024 + t2b +
                  pass * 256 + t8) = *(const f16x8*)&lds[kcl * 264 + t8];
      }
      __syncthreads();  // staging reads done before next pass / wbuf reuse
    }
  }

  // ---- Q or K main: continuous half-chunk pipeline over 40 chunks --------
  f32x4 aq[4][8];
#pragma unroll
  for (int rt = 0; rt < 4; ++rt)
#pragma unroll
    for (int i = 0; i < 8; ++i)
#pragma unroll
      for (int r = 0; r < 4; ++r) { aq[rt][i][r] = 0.f; }

  const int64_t wbase = wlane + (int64_t)o0 * 128;
  // half H (0: ntl 0-1, 1: ntl 2-3) of chunk (J, KK, NTG); J may be runtime
#define ISSUE_HALF(J, KK, NTG, H)                                       \
  {                                                                     \
    _Pragma("unroll")                                                   \
    for (int ntl2 = 0; ntl2 < 2; ++ntl2) {                              \
      const int ntl_ = (H) * 2 + ntl2;                                  \
      const int64_t o_ = wbase + (int64_t)(J) * 131072 + (KK) * 32 +    \
                         (int64_t)(((NTG) * 4 + ntl_) * 16) * 128;      \
      dma16(Wh + o_, wbuf + w * 4096 + ntl_ * 1024);                    \
      dma16(Wl + o_, wbuf + w * 4096 + ntl_ * 1024 + 512);              \
    }                                                                   \
  }

  ISSUE_HALF(0, 0, 0, 0)
  ISSUE_HALF(0, 0, 0, 1)

  const bool z0 = (tloc == 0);
  for (int j = 0; j < 5; ++j) {
    f16x8 ah[4], al[4];
#pragma unroll
    for (int c = 0; c < 8; ++c) {
      const int kk = c >> 1, ntg = c & 1;
      if (ntg == 0) {
        // hoisted A fragments for this (j,kk): independent of nt
#pragma unroll
        for (int rt = 0; rt < 4; ++rt) {
          ah[rt] = *(const f16x8*)&xbuf[(rt * 16 + lo + j) * 264 + kk * 32 +
                                        quad * 8];
          al[rt] = *(const f16x8*)&xbuf[(rt * 16 + lo + j) * 264 + 128 +
                                        kk * 32 + quad * 8];
        }
        if (z0 && (lo + j < 4)) {
#pragma unroll
          for (int e = 0; e < 8; ++e) { ah[0][e] = (f16)0; al[0][e] = (f16)0; }
        }
      }
      // next chunk coordinates (pipeline crosses kk and j boundaries)
      const int nj = (c == 7) ? j + 1 : j;
      const int nkk = (c == 7) ? 0 : ((c + 1) >> 1);
      const int nntg = (c == 7) ? 0 : ((c + 1) & 1);
      const bool more = (c < 7) || (j < 4);

      wait_vm4();                 // half0(j,c) landed; 4+ stay in flight
#pragma unroll
      for (int ntl = 0; ntl < 2; ++ntl) {
        const int nt = ntg * 4 + ntl;
        const f16x8 bh = *(const f16x8*)&wbuf[w * 4096 + ntl * 1024 +
                                              quad * 128 + lo * 8];
        const f16x8 bl = *(const f16x8*)&wbuf[w * 4096 + ntl * 1024 + 512 +
                                              quad * 128 + lo * 8];
#pragma unroll
        for (int rt = 0; rt < 4; ++rt) {
          aq[rt][nt] = MFMA16(ah[rt], bh, aq[rt][nt]);
          aq[rt][nt] = MFMA16(ah[rt], bl, aq[rt][nt]);
          aq[rt][nt] = MFMA16(al[rt], bh, aq[rt][nt]);
        }
      }
      wait_lgkm0();               // half0 reads sampled before slot reuse
      if (more) ISSUE_HALF(nj, nkk, nntg, 0)

      if (c == 7) {               // last chunk of j: maybe nothing behind
        if (j == 4) wait_vm0(); else wait_vm4();
      } else {
        wait_vm4();               // half1(j,c) landed
      }
#pragma unroll
      for (int ntl = 2; ntl < 4; ++ntl) {
        const int nt = ntg * 4 + ntl;
        const f16x8 bh = *(const f16x8*)&wbuf[w * 4096 + ntl * 1024 +
                                              quad * 128 + lo * 8];
        const f16x8 bl = *(const f16x8*)&wbuf[w * 4096 + ntl * 1024 + 512 +
                                              quad * 128 + lo * 8];
#pragma unroll
        for (int rt = 0; rt < 4; ++rt) {
          aq[rt][nt] = MFMA16(ah[rt], bh, aq[rt][nt]);
          aq[rt][nt] = MFMA16(ah[rt], bl, aq[rt][nt]);
          aq[rt][nt] = MFMA16(al[rt], bh, aq[rt][nt]);
        }
      }
      wait_lgkm0();               // half1 reads sampled before slot reuse
      if (more) ISSUE_HALF(nj, nkk, nntg, 1)
    }
  }
#undef ISSUE_HALF

  const float SC = 0.29730177875068026f;  // 128^-0.25
#pragma unroll
  for (int nt = 0; nt < 8; ++nt) {
    const int o = o0 + nt * 16 + lo;
    const float vb = bias[o];
#pragma unroll
    for (int rt = 0; rt < 4; ++rt)
#pragma unroll
      for (int r = 0; r < 4; ++r) aq[rt][nt][r] = (aq[rt][nt][r] + vb) * SC;
  }

  if (!isK) {
    STAGE_QK(q3h, 0, (f16)aq[rt][nt][r])
    STAGE_QK(q3h, 1, (f16)aq[rt][nt][r])
    STAGE_QK(q3l, 0, (f16)(aq[rt][nt][r] - (float)(f16)aq[rt][nt][r]))
    STAGE_QK(q3l, 1, (f16)(aq[rt][nt][r] - (float)(f16)aq[rt][nt][r]))
  } else {
    STAGE_QK(k3h, 0, (f16)aq[rt][nt][r])
    STAGE_QK(k3h, 1, (f16)aq[rt][nt][r])
    STAGE_QK(k3l, 0, (f16)(aq[rt][nt][r] - (float)(f16)aq[rt][nt][r]))
    STAGE_QK(k3l, 1, (f16)(aq[rt][nt][r] - (float)(f16)aq[rt][nt][r]))
  }
}

// ---------------- K234: 32 Q-rows/block, Q staged once, continuous K -------
// R17 structure with the ev-spill removed: phase 2b computes only the
// softmax SUMS (inv[2][2]); the P writes recompute ev from the still-live
// keys per half (bit-identical: same inputs -> same __expf -> same f16).
// Keys j=0..7 die at the P half-0 write, so the live set across the long
// PV half-0 MFMA loop is ~keys[8..15]+oa (was ev[64]+keys -> 18 MB scratch
// eviction, WRITE_SIZE 34.6 MB in R17). +64 exps/thread is the trade.
__global__ __launch_bounds__(512, 4) void k234_attn(
    const f16* __restrict__ q3h, const f16* __restrict__ q3l,
    const f16* __restrict__ k3h, const f16* __restrict__ k3l,
    const f16* __restrict__ v3T, f16* __restrict__ A) {
  __shared__ __align__(16) char smem[66560];
  float* const SbQ = (float*)smem;                 // 16 x 268 f32 (phase 1)
  f16* const PbufA = (f16*)smem;                   // grp0: 16 x 520 (phase 3)
  f16* const qlds = (f16*)(smem + 17152);          // 16 slots x 512 (phase 1)
  f16* const PbufB = (f16*)(smem + 17152);         // grp1: 16 x 520 (phase 3)
  f16* const kbuf = (f16*)(smem + 33792);          // 32768 B: 8w x 4 x 512
  const int tid = threadIdx.x;
  const int w = tid >> 6, lane = tid & 63;
  const int quad = lane >> 4, lo = lane & 15;
  const int qd = lane & 3, cit = lane >> 2;       // DMA lanes: [row][piece]
  const int qsw = qd ^ ((cit >> 1) & 3);          // bank-swizzled piece
  const int fro = (lo * 4 + (quad ^ ((lo >> 1) & 3))) * 8;  // fragment read
  // bijective XCD remap: 2048 blocks = 8 xcd * 8 m * 32 r0-blocks
  const int hid = blockIdx.y * 32 + blockIdx.x;
  const int m = (hid & 7) * 8 + ((hid >> 3) >> 5);
  const int r0 = ((hid >> 3) & 31) * 32;

  unsigned key[2][2][16];          // [grp][rr][j]
  unsigned kmn[2][2];
#pragma unroll
  for (int g = 0; g < 2; ++g)
#pragma unroll
    for (int rr = 0; rr < 2; ++rr) kmn[g][rr] = 0xFFFFFFFFu;

  // ---- stage ALL Q fragments once: slot = seg*4 + grp*2 + h ---------------
  {
#pragma unroll
    for (int s2 = 0; s2 < 2; ++s2) {
      const int sl = w * 2 + s2;
      const int seg = sl >> 2, grp_ = (sl >> 1) & 1, h_ = sl & 1;
      const f16* qsrc = (h_ ? q3l : q3h) +
          ((int64_t)m * 1024 + r0 + grp_ * 16 + lo) * 128 + seg * 32 +
          quad * 8;
      dma16(qsrc, qlds + sl * 512);
    }
    wait_vm0();                    // own 2 DMAs landed
    __syncthreads();               // all Q slots visible to all waves
  }

  // K chunk (HALF, C): rows (HALF*512 + (C&3)*128 + w*16 + ..), cols seg*32
#define KISS(HALF, C, PAIR)                                              \
  {                                                                      \
    const int64_t rowg =                                                 \
        (int64_t)(m * 1024 + (HALF) * 512 + ((C) & 3) * 128 + w * 16 +   \
                  cit) * 128 + ((C) >> 2) * 32 + qsw * 8;                \
    dma16(k3h + rowg, kbuf + (w * 4 + (PAIR) * 2) * 512);                \
    dma16(k3l + rowg, kbuf + (w * 4 + (PAIR) * 2 + 1) * 512);            \
  }

  // ---- phase 1: S = Q @ K^T, one continuous ping-pong stream --------------
  KISS(0, 0, 0)
  KISS(0, 1, 1)
#pragma unroll
  for (int half = 0; half < 2; ++half) {
    f32x4 acc[2][4];               // [grp][cc]
#pragma unroll
    for (int g = 0; g < 2; ++g)
#pragma unroll
      for (int i = 0; i < 4; ++i)
#pragma unroll
        for (int r = 0; r < 4; ++r) acc[g][i][r] = 0.f;

#pragma unroll
    for (int c = 0; c < 16; ++c) {
      const int g = half * 16 + c;
      if (g == 31) wait_vm0();     // last chunk of the block's K stream
      else wait_vm2();             // chunk g landed; next pair in flight
      const int pair = c & 1;      // == g & 1
      const int seg = c >> 2, cc = c & 3;
      const f16x8 qh0 = ldfrag(qlds + (seg * 4 + 0) * 512 + lane * 8);
      const f16x8 ql0 = ldfrag(qlds + (seg * 4 + 1) * 512 + lane * 8);
      const f16x8 qh1 = ldfrag(qlds + (seg * 4 + 2) * 512 + lane * 8);
      const f16x8 ql1 = ldfrag(qlds + (seg * 4 + 3) * 512 + lane * 8);
      const f16x8 bh = *(const f16x8*)(kbuf + (w * 4 + pair * 2) * 512 + fro);
      const f16x8 bl =
          *(const f16x8*)(kbuf + (w * 4 + pair * 2 + 1) * 512 + fro);
      acc[0][cc] = MFMA16(qh0, bh, acc[0][cc]);
      acc[0][cc] = MFMA16(qh0, bl, acc[0][cc]);
      acc[0][cc] = MFMA16(ql0, bh, acc[0][cc]);
      acc[1][cc] = MFMA16(qh1, bh, acc[1][cc]);
      acc[1][cc] = MFMA16(qh1, bl, acc[1][cc]);
      acc[1][cc] = MFMA16(ql1, bh, acc[1][cc]);
      wait_lgkm0();                // reads sampled before pair re-targeted
      const int gn = g + 2;
      if (gn < 32) KISS(gn >> 4, gn & 15, gn & 1)
    }

    // write S + snapshot keys, per (group, 256-col quarter); half-1's first
    // K pair is already in flight and rides over these barriers.
#pragma unroll
    for (int grp = 0; grp < 2; ++grp) {
#pragma unroll
      for (int q = 0; q < 2; ++q) {
#pragma unroll
        for (int c2 = 0; c2 < 2; ++c2)
#pragma unroll
          for (int r = 0; r < 4; ++r)
            SbQ[(quad * 4 + r) * 268 + c2 * 128 + w * 16 + lo] =
                acc[grp][q * 2 + c2][r];
        __syncthreads();   // cross-wave: snapshot reads other waves' columns
#pragma unroll
        for (int rr = 0; rr < 2; ++rr) {
          const float4 f4 =
              *(const float4*)(SbQ + (w * 2 + rr) * 268 + lane * 4);
          const float fe[4] = {f4.x, f4.y, f4.z, f4.w};
#pragma unroll
          for (int e = 0; e < 4; ++e) {
            const unsigned u = __builtin_bit_cast(unsigned, fe[e]);
            const unsigned k = (u & 0x80000000u) ? ~u : (u | 0x80000000u);
            key[grp][rr][half * 8 + q * 4 + e] = k;
            kmn[grp][rr] = min(kmn[grp][rr], k);
          }
        }
        __syncthreads();  // key reads done before next quarter overwrites
      }
    }
  }
#undef KISS

  // ---- pre-issue V kb0/kb1; latency hides under the radix ----------------
  const int64_t vrow = (int64_t)(m * 128 + w * 16 + cit) * 1024;
  const int nkbM = ((r0 + 16) >> 6) + 1;   // grp1 span >= grp0 span
#define VISSUE(KB, PAIR)                                                 \
  {                                                                      \
    dma16(v3T + vrow + (KB) * 64 + qsw * 8,                              \
          kbuf + (w * 4 + (PAIR) * 2) * 512);                            \
    dma16(v3T + vrow + (KB) * 64 + 32 + qsw * 8,                         \
          kbuf + (w * 4 + (PAIR) * 2 + 1) * 512);                       \
  }
  VISSUE(0, 0)
  if (nkbM > 1) VISSUE(1, 1)

  // ---- phase 2a: row-min reduce + exact top-64 radix (4 rows/wave) -------
#pragma unroll
  for (int off = 32; off; off >>= 1) {
#pragma unroll
    for (int g = 0; g < 2; ++g)
#pragma unroll
      for (int rr = 0; rr < 2; ++rr)
        kmn[g][rr] = min(kmn[g][rr],
                         (unsigned)__shfl_xor((int)kmn[g][rr], off));
  }
  unsigned th[2][2] = {{0u, 0u}, {0u, 0u}};
  {
    bool dn[2][2] = {{false, false}, {false, false}};
    for (int b = 31; b >= 0; --b) {
      bool all = true;
#pragma unroll
      for (int g = 0; g < 2; ++g)
#pragma unroll
        for (int rr = 0; rr < 2; ++rr) {
          if (!dn[g][rr]) {
            const unsigned c = th[g][rr] | (1u << b);
            int cnt = 0;
#pragma unroll
            for (int i = 0; i < 16; ++i)
              cnt += (int)__popcll(__ballot(key[g][rr][i] >= c));
            if (cnt >= 64) { th[g][rr] = c; if (cnt == 64) dn[g][rr] = true; }
          }
          all = all && dn[g][rr];
        }
      if (all) break;
    }
  }

  // ev recompute helper: bit-identical exp from still-live keys
#define EVJ(G, RR, J, OUTX)                                              \
  {                                                                      \
    const unsigned kth_ = th[(G)][(RR)];                                 \
    const unsigned kmv_ = kmn[(G)][(RR)];                                \
    const int t2_ = r0 + (G) * 16 + w * 2 + (RR);                        \
    const unsigned umn_ =                                                \
        (kmv_ & 0x80000000u) ? (kmv_ ^ 0x80000000u) : ~kmv_;             \
    const float mn_ = __builtin_bit_cast(float, umn_);                   \
    const unsigned ukv_ =                                                \
        (kth_ & 0x80000000u) ? (kth_ ^ 0x80000000u) : ~kth_;             \
    const float kv_ = __builtin_bit_cast(float, ukv_);                   \
    const int s_ = ((J) >> 2) * 256 + lane * 4 + ((J) & 3);              \
    const unsigned k_ = key[(G)][(RR)][(J)];                             \
    const unsigned uu_ = (k_ & 0x80000000u) ? (k_ ^ 0x80000000u) : ~k_;  \
    const float f_ = __builtin_bit_cast(float, uu_);                     \
    const float ww_ = (k_ >= kth_) ? f_ : mn_;                           \
    (OUTX) = (s_ <= t2_) ? __expf(ww_ - kv_) : 0.f;                      \
  }

  // ---- phase 2b: softmax SUMS only (ev recomputed at the P writes) -------
  float inv[2][2];
#pragma unroll
  for (int g = 0; g < 2; ++g)
#pragma unroll
    for (int rr = 0; rr < 2; ++rr) {
      float sum = 0.f;
#pragma unroll
      for (int j = 0; j < 16; ++j) {
        float x;
        EVJ(g, rr, j, x)
        sum += x;
      }
      for (int off = 32; off; off >>= 1) sum += __shfl_xor(sum, off);
      inv[g][rr] = 1.0f / sum;
    }

  // ---- phase 3: ONE V stream, 4 MFMA per chunk (2 per group) -------------
  {
    const int nkb0h = nkbM < 8 ? nkbM : 8;     // half-0 span
    // write P half 0 for both groups (recompute ev j=0..7; keys 0..7 die)
#pragma unroll
    for (int g = 0; g < 2; ++g) {
      f16* const pb = g ? PbufB : PbufA;
#pragma unroll
      for (int rr = 0; rr < 2; ++rr) {
        f16* prow = pb + (w * 2 + rr) * 520;
#pragma unroll
        for (int i2 = 0; i2 < 2; ++i2) {
          f16x4 pk;
#pragma unroll
          for (int e = 0; e < 4; ++e) {
            float x;
            EVJ(g, rr, i2 * 4 + e, x)
            pk[e] = (f16)(x * inv[g][rr]);
          }
          *(f16x4*)(prow + i2 * 256 + lane * 4) = pk;
        }
      }
    }
    __syncthreads();  // P half-0 visible to all waves

    f32x4 oaA0, oaA1, oaB0, oaB1;
#pragma unroll
    for (int r = 0; r < 4; ++r) {
      oaA0[r] = 0.f; oaA1[r] = 0.f; oaB0[r] = 0.f; oaB1[r] = 0.f;
    }
    for (int kb = 0; kb < nkb0h; ++kb) {
      if (kb + 1 < nkb0h) wait_vm2();  // kb landed; kb+1 stays in flight
      else wait_vm0();
      const int pair = kb & 1;
      {
        const f16x8 vf0 =
            *(const f16x8*)(kbuf + (w * 4 + pair * 2) * 512 + fro);
        const f16x8 vf1 =
            *(const f16x8*)(kbuf + (w * 4 + pair * 2 + 1) * 512 + fro);
        const f16x8 aA0 =
            *(const f16x8*)(PbufA + lo * 520 + kb * 64 + quad * 8);
        const f16x8 aA1 =
            *(const f16x8*)(PbufA + lo * 520 + kb * 64 + 32 + quad * 8);
        const f16x8 aB0 =
            *(const f16x8*)(PbufB + lo * 520 + kb * 64 + quad * 8);
        const f16x8 aB1 =
            *(const f16x8*)(PbufB + lo * 520 + kb * 64 + 32 + quad * 8);
        oaA0 = MFMA16(aA0, vf0, oaA0);
        oaA1 = MFMA16(aA1, vf1, oaA1);
        oaB0 = MFMA16(aB0, vf0, oaB0);
        oaB1 = MFMA16(aB1, vf1, oaB1);
      }
      wait_lgkm0();                    // reads sampled before slot reuse
      if (kb + 2 < nkb0h) VISSUE(kb + 2, pair)
    }

    if (nkbM > 8) {
      // pre-issue half-1 V (rides over the P rewrite)
      VISSUE(8, 0)
      if (nkbM > 9) VISSUE(9, 1)
      __syncthreads();  // PV half-0 af reads done before P rewrite
      // write P half 1 (recompute ev j=8..15 from keys)
#pragma unroll
      for (int g = 0; g < 2; ++g) {
        f16* const pb = g ? PbufB : PbufA;
#pragma unroll
        for (int rr = 0; rr < 2; ++rr) {
          f16* prow = pb + (w * 2 + rr) * 520;
#pragma unroll
          for (int i2 = 0; i2 < 2; ++i2) {
            f16x4 pk;
#pragma unroll
            for (int e = 0; e < 4; ++e) {
              float x;
              EVJ(g, rr, 8 + i2 * 4 + e, x)
              pk[e] = (f16)(x * inv[g][rr]);
            }
            *(f16x4*)(prow + i2 * 256 + lane * 4) = pk;
          }
        }
      }
      __syncthreads();  // P half-1 visible
      for (int kb = 8; kb < nkbM; ++kb) {
        if (kb + 1 < nkbM) wait_vm2();
        else wait_vm0();
        const int pair = kb & 1;
        {
          const f16x8 vf0 =
              *(const f16x8*)(kbuf + (w * 4 + pair * 2) * 512 + fro);
          const f16x8 vf1 =
              *(const f16x8*)(kbuf + (w * 4 + pair * 2 + 1) * 512 + fro);
          const f16x8 aA0 =
              *(const f16x8*)(PbufA + lo * 520 + (kb - 8) * 64 + quad * 8);
          const f16x8 aA1 =
              *(const f16x8*)(PbufA + lo * 520 + (kb - 8) * 64 + 32 + quad * 8);
          const f16x8 aB0 =
              *(const f16x8*)(PbufB + lo * 520 + (kb - 8) * 64 + quad * 8);
          const f16x8 aB1 =
              *(const f16x8*)(PbufB + lo * 520 + (kb - 8) * 64 + 32 + quad * 8);
          oaA0 = MFMA16(aA0, vf0, oaA0);
          oaA1 = MFMA16(aA1, vf1, oaA1);
          oaB0 = MFMA16(aB0, vf0, oaB0);
          oaB1 = MFMA16(aB1, vf1, oaB1);
        }
        wait_lgkm0();
        if (kb + 2 < nkbM) VISSUE(kb + 2, pair)
      }
    }

#pragma unroll
    for (int r = 0; r < 4; ++r) {
      A[((int64_t)m * 1024 + r0 + quad * 4 + r) * 128 + w * 16 + lo] =
          (f16)(oaA0[r] + oaA1[r]);
      A[((int64_t)m * 1024 + r0 + 16 + quad * 4 + r) * 128 + w * 16 + lo] =
          (f16)(oaB0[r] + oaB1[r]);
    }
  }
#undef VISSUE
#undef EVJ
}

// ---------------- K5: gather + output projection + bias --------------------
__global__ __launch_bounds__(256) void k5_proj(
    const f16* __restrict__ A, const f16* __restrict__ Wub,
    const float* __restrict__ bu, float* __restrict__ out) {
  const int w = threadIdx.x >> 6, lane = threadIdx.x & 63;
  const int quad = lane >> 4, lo = lane & 15;
  const int rt = w & 1, ch = w >> 1;
  const int r0 = blockIdx.x * 32 + rt * 16;  // row in [0,8192) = b*1024 + t2
  const int r = r0 + lo;
  const int bI = r >> 10, t2 = r & 1023;

  f32x4 acc[4];
#pragma unroll
  for (int i = 0; i < 4; ++i)
#pragma unroll
    for (int rr = 0; rr < 4; ++rr) acc[i][rr] = 0.f;

#pragma unroll 2
  for (int kk = 0; kk < 32; ++kk) {
    const int o = kk * 32 + quad * 8;  // feature index 0..1023
    const int j = o >> 7, kc = o & 127;
    f16x8 a = ldfrag(A + (((int64_t)(bI * 8 + j) * 1024 + t2) * 128 + kc));
    f16x8 wb[4];
#pragma unroll
    for (int nt = 0; nt < 4; ++nt)
      wb[nt] = ldfrag(Wub + (int64_t)(ch * 64 + nt * 16 + lo) * 1024 + o);
#pragma unroll
    for (int nt = 0; nt < 4; ++nt) acc[nt] = MFMA16(a, wb[nt], acc[nt]);
  }
#pragma unroll
  for (int nt = 0; nt < 4; ++nt) {
    const int col = ch * 64 + nt * 16 + lo;
    const float bias = bu[col];
#pragma unroll
    for (int rr = 0; rr < 4; ++rr) {
      const int row = r0 + quad * 4 + rr;
      out[(int64_t)row * 128 + col] = acc[nt][rr] + bias;
    }
  }
}

// ---------------- launcher --------------------------------------------------
extern "C" void kernel_launch(void* const* d_in, const int* in_sizes, int n_in,
                              void* d_out, int out_size, void* d_ws, size_t ws_size,
                              hipStream_t stream) {
  const float* x  = (const float*)d_in[0];
  const float* Wq = (const float*)d_in[1];
  const float* bq = (const float*)d_in[2];
  const float* Wk = (const float*)d_in[3];
  const float* bk = (const float*)d_in[4];
  const float* Wv = (const float*)d_in[5];
  const float* bv = (const float*)d_in[6];
  const float* Wu = (const float*)d_in[7];
  const float* bu = (const float*)d_in[8];
  float* out = (float*)d_out;

  char* ws = (char*)d_ws;
  f16* xh  = (f16*)ws;  ws += 2097152;
  f16* xl  = (f16*)ws;  ws += 2097152;
  f16* Wqh = (f16*)ws;  ws += 1310720;
  f16* Wql = (f16*)ws;  ws += 1310720;
  f16* Wkh = (f16*)ws;  ws += 1310720;
  f16* Wkl = (f16*)ws;  ws += 1310720;
  f16* Wvb = (f16*)ws;  ws += 262144;
  f16* Wub = (f16*)ws;  ws += 262144;
  f16* q3h = (f16*)ws;  ws += 16777216;           // 64*1024*128 fp16
  f16* q3l = (f16*)ws;  ws += 16777216;
  f16* k3h = (f16*)ws;  ws += 16777216;
  f16* k3l = (f16*)ws;  ws += 16777216;
  f16* v3T = (f16*)ws;  ws += 16777216;
  f16* A   = (f16*)ws;  ws += 16777216;           // total ~105.5 MB

  // K0: repack (exactly 2621440 threads = 10240 * 256)
  k0_prep<<<10240, 256, 0, stream>>>(x, Wq, Wk, Wv, Wu,
                                     xh, xl, Wqh, Wql, Wkh, Wkl, Wvb, Wub);

  // K1: convs + scramble; 64 T-rows/block, pipelined weight stream
  k1_conv<<<dim3(128, 2, 2), 256, 0, stream>>>(xh, xl, Wqh, Wql, Wkh, Wkl, Wvb,
                                               bq, bk, bv, q3h, q3l, k3h, k3l,
                                               v3T);

  // K234: Q staged once, continuous K, shared V, spill-free softmax
  k234_attn<<<dim3(32, 64), 512, 0, stream>>>(q3h, q3l, k3h, k3l, v3T, A);

  // K5: projection (8192 rows / 32 per block)
  k5_proj<<<256, 256, 0, stream>>>(A, Wub, bu, out);

  (void)in_sizes; (void)n_in; (void)out_size; (void)ws_size;
}

// Round 19
// 371.371 us; speedup vs baseline: 1.0551x; 1.0551x over previous
//
#include <hip/hip_runtime.h>
#include <hip/hip_fp16.h>
#include <cstdint>

using f16 = _Float16;
typedef __attribute__((ext_vector_type(8))) _Float16 f16x8;
typedef __attribute__((ext_vector_type(4))) _Float16 f16x4;
typedef __attribute__((ext_vector_type(4))) float f32x4;

#define MFMA16(a, b, c) __builtin_amdgcn_mfma_f32_16x16x32_f16((a), (b), (c), 0, 0, 0)

__device__ __forceinline__ f16x8 ldfrag(const f16* p) { return *(const f16x8*)p; }

// async global->LDS DMA, 16 B per lane; lds dest = wave-uniform base + lane*16
__device__ __forceinline__ void dma16(const f16* g, f16* l) {
  __builtin_amdgcn_global_load_lds(
      (const __attribute__((address_space(1))) void*)g,
      (__attribute__((address_space(3))) void*)l, 16, 0, 0);
}
// explicit per-wave fences (do NOT rely on compiler LDS-DMA modeling)
__device__ __forceinline__ void wait_vm0() {
  asm volatile("s_waitcnt vmcnt(0)" ::: "memory");
}
__device__ __forceinline__ void wait_lgkm0() {
  asm volatile("s_waitcnt lgkmcnt(0)" ::: "memory");
}
__device__ __forceinline__ void wait_vm4() {
  asm volatile("s_waitcnt vmcnt(4)" ::: "memory");
}
__device__ __forceinline__ void wait_vm2() {
  asm volatile("s_waitcnt vmcnt(2)" ::: "memory");
}

// Problem constants: B=8, T=1024, K=128, H=8 -> M = B*H = 64 scrambled batches.
static const int64_t NX = 1048576;   // x elements: 8*1024*128
static const int64_t NW = 655360;    // Wq/Wk elements: 1024*128*5
static const int64_t NV = 131072;    // Wv / Wu elements: 1024*128

// ---------------- K0: split-convert/repack weights and x to fp16 hi/lo -----
__global__ __launch_bounds__(256) void k0_prep(
    const float* __restrict__ x, const float* __restrict__ Wq,
    const float* __restrict__ Wk, const float* __restrict__ Wv,
    const float* __restrict__ Wu,
    f16* __restrict__ xh, f16* __restrict__ xl,
    f16* __restrict__ Wqh, f16* __restrict__ Wql,
    f16* __restrict__ Wkh, f16* __restrict__ Wkl,
    f16* __restrict__ Wvb, f16* __restrict__ Wub) {
  int64_t i = (int64_t)blockIdx.x * 256 + threadIdx.x;  // grid sized exactly
  if (i < NX) {
    const float v = x[i];
    const f16 h = (f16)v;
    xh[i] = h; xl[i] = (f16)(v - (float)h);
  } else if (i < NX + NW) {
    int64_t d = i - NX;
    int j = (int)(d >> 17);
    int rem = (int)(d & 131071);
    int o = rem >> 7, c = rem & 127;
    const float v = Wq[(int64_t)(o * 128 + c) * 5 + j];   // layout [j][o][c]
    const f16 h = (f16)v;
    Wqh[d] = h; Wql[d] = (f16)(v - (float)h);
  } else if (i < NX + 2 * NW) {
    int64_t d = i - NX - NW;
    int j = (int)(d >> 17);
    int rem = (int)(d & 131071);
    int o = rem >> 7, c = rem & 127;
    const float v = Wk[(int64_t)(o * 128 + c) * 5 + j];
    const f16 h = (f16)v;
    Wkh[d] = h; Wkl[d] = (f16)(v - (float)h);
  } else if (i < NX + 2 * NW + NV) {
    int64_t d = i - NX - 2 * NW;
    Wvb[d] = (f16)Wv[d];                                // [o][c]
  } else {
    int64_t d = i - NX - 2 * NW - NV;
    Wub[d] = (f16)Wu[d];                                // [c][o]
  }
}

// ---------------- K1: causal convs, 64 T-rows/block ------------------------
// A-frags hoisted per (j,kk); continuous half-chunk pipelined weight stream.
// V pass ping-pong pipelined (4 KB in flight during compute, vm4 waits).
#define STAGE_QK(DST, PASS, VALEXPR)                                    \
  {                                                                     \
    __syncthreads();                                                    \
    _Pragma("unroll")                                                   \
    for (int nt = 0; nt < 8; ++nt) {                                    \
      const int o = o0 + nt * 16 + lo;                                  \
      const int kcl = (o >> 3) & 63, hh = o & 7;                        \
      _Pragma("unroll")                                                 \
      for (int rtl = 0; rtl < 2; ++rtl) {                               \
        const int rt = (PASS) * 2 + rtl;                                \
        _Pragma("unroll")                                               \
        for (int r = 0; r < 4; ++r) {                                   \
          const int t2l = (rtl * 16 + quad * 4 + r) * 8 + hh;           \
          lds[t2l * 72 + kcl] = (VALEXPR);                              \
        }                                                               \
      }                                                                 \
    }                                                                   \
    __syncthreads();                                                    \
    _Pragma("unroll")                                                   \
    for (int p = 0; p < 8; ++p) {                                       \
      const int idx = p * 256 + tid;                                    \
      const int a = idx >> 3, c8 = (idx & 7) * 8;                       \
      *(f16x8*)(DST + ((int64_t)m * 1024 + t2b + (PASS) * 256 + a) * 128 + \
                half * 64 + c8) = *(const f16x8*)&lds[a * 72 + c8];     \
    }                                                                   \
  }

__global__ __launch_bounds__(256) void k1_conv(
    const f16* __restrict__ xh, const f16* __restrict__ xl,
    const f16* __restrict__ Wqh, const f16* __restrict__ Wql,
    const f16* __restrict__ Wkh, const f16* __restrict__ Wkl,
    const f16* __restrict__ Wvb,
    const float* __restrict__ bq, const float* __restrict__ bk,
    const float* __restrict__ bv,
    f16* __restrict__ q3h, f16* __restrict__ q3l,
    f16* __restrict__ k3h, f16* __restrict__ k3l,
    f16* __restrict__ v3T) {
  __shared__ f16 shm[36384];      // 72.8 KB: [0,18432) wbuf/stage, rest xbuf
  f16* const wbuf = shm;
  f16* const xbuf = shm + 18432;  // 68 rows x 264 f16
  f16* const lds  = shm;          // staging alias
  const int tid = threadIdx.x;
  const int w = tid >> 6, lane = tid & 63;
  const int quad = lane >> 4, lo = lane & 15;
  const int r0 = blockIdx.x * 64;     // rows r0..r0+63 (same b, same m)
  const int bb = r0 >> 10;
  const int m  = r0 >> 7;
  const int t2b = (r0 & 127) * 8;     // 0 or 512
  const int tloc = r0 & 1023;
  const int half = blockIdx.y;        // which 512-channel half
  const int isK = blockIdx.z;         // 0 = Q (+V), 1 = K
  const int o0 = half * 512 + w * 128;

  const f16* Wh = isK ? Wkh : Wqh;
  const f16* Wl = isK ? Wkl : Wql;
  const float* bias = isK ? bk : bq;

  // ---- stage x rows [tloc-4, tloc+64) (clamped at batch start) ----
#pragma unroll
  for (int p = 0; p < 9; ++p) {
    const int u = p * 256 + tid;           // f16x8 unit
    if (u < 2176) {
      const int row = u >> 5, tz = (u >> 4) & 1, c8 = (u & 15) * 8;
      int lt = tloc - 4 + row;
      if (lt < 0) lt = 0;
      const f16* src = (tz ? xl : xh) + ((int64_t)(bb * 1024 + lt)) * 128 + c8;
      *(f16x8*)&xbuf[row * 264 + tz * 128 + c8] = *(const f16x8*)src;
    }
  }
  __syncthreads();

  // per-lane gather offset within a 16n x 128c fragment block
  const int64_t wlane = (int64_t)(lane & 15) * 128 + (lane >> 4) * 8;

  // ---- V pass (Q-blocks only): pointwise tap, hi only; ping-pong stream --
  if (!isK) {
    f32x4 av[4][8];
#pragma unroll
    for (int rt = 0; rt < 4; ++rt)
#pragma unroll
      for (int i = 0; i < 8; ++i)
#pragma unroll
        for (int r = 0; r < 4; ++r) av[rt][i][r] = 0.f;

    // unit u (= output tile o0+u*16) -> wbuf region (u&1)*2048
#define VUNIT(U)                                                        \
  {                                                                     \
    const int64_t vsrc = (int64_t)(o0 + (U) * 16) * 128 + wlane;        \
    _Pragma("unroll")                                                   \
    for (int kk = 0; kk < 4; ++kk)                                      \
      dma16(Wvb + vsrc + kk * 32,                                       \
            wbuf + w * 4096 + ((U) & 1) * 2048 + kk * 512);             \
  }
    VUNIT(0)
    VUNIT(1)
#pragma unroll
    for (int u = 0; u < 8; ++u) {
      if (u < 7) wait_vm4();   // unit u landed; unit u+1 stays in flight
      else wait_vm0();
#pragma unroll
      for (int kk = 0; kk < 4; ++kk) {
        f16x8 a[4];
#pragma unroll
        for (int rt = 0; rt < 4; ++rt)
          a[rt] = *(const f16x8*)&xbuf[(rt * 16 + lo + 4) * 264 + kk * 32 +
                                       quad * 8];
        const f16x8 bv8 = *(const f16x8*)&wbuf[w * 4096 + (u & 1) * 2048 +
                                               kk * 512 + quad * 128 + lo * 8];
#pragma unroll
        for (int rt = 0; rt < 4; ++rt)
          av[rt][u] = MFMA16(a[rt], bv8, av[rt][u]);
      }
      wait_lgkm0();  // own ds_reads sampled before region re-targeted
      if (u + 2 < 8) VUNIT(u + 2)
    }
#undef VUNIT
    __syncthreads();  // all waves done with wbuf before cross-wave staging
    // bias + stage v3T via LDS [kcl][t2l] (stride 264), two 256-col passes
#pragma unroll
    for (int pass = 0; pass < 2; ++pass) {
#pragma unroll
      for (int nt = 0; nt < 8; ++nt) {
        const int o = o0 + nt * 16 + lo;
        const float vbv = bv[o];
        const int kcl = (o >> 3) & 63, hh = o & 7;
#pragma unroll
        for (int rtl = 0; rtl < 2; ++rtl)
#pragma unroll
          for (int r = 0; r < 4; ++r) {
            const int t2l = (rtl * 16 + quad * 4 + r) * 8 + hh;
            lds[kcl * 264 + t2l] = (f16)(av[pass * 2 + rtl][nt][r] + vbv);
          }
      }
      __syncthreads();
#pragma unroll
      for (int p = 0; p < 8; ++p) {
        const int idx = p * 256 + tid;
        const int kcl = idx >> 5, t8 = (idx & 31) * 8;
        *(f16x8*)(v3T + ((int64_t)m * 128 + half * 64 + kcl) * 1024 + t2b +
                  pass * 256 + t8) = *(const f16x8*)&lds[kcl * 264 + t8];
      }
      __syncthreads();  // staging reads done before next pass / wbuf reuse
    }
  }

  // ---- Q or K main: continuous half-chunk pipeline over 40 chunks --------
  f32x4 aq[4][8];
#pragma unroll
  for (int rt = 0; rt < 4; ++rt)
#pragma unroll
    for (int i = 0; i < 8; ++i)
#pragma unroll
      for (int r = 0; r < 4; ++r) { aq[rt][i][r] = 0.f; }

  const int64_t wbase = wlane + (int64_t)o0 * 128;
  // half H (0: ntl 0-1, 1: ntl 2-3) of chunk (J, KK, NTG); J may be runtime
#define ISSUE_HALF(J, KK, NTG, H)                                       \
  {                                                                     \
    _Pragma("unroll")                                                   \
    for (int ntl2 = 0; ntl2 < 2; ++ntl2) {                              \
      const int ntl_ = (H) * 2 + ntl2;                                  \
      const int64_t o_ = wbase + (int64_t)(J) * 131072 + (KK) * 32 +    \
                         (int64_t)(((NTG) * 4 + ntl_) * 16) * 128;      \
      dma16(Wh + o_, wbuf + w * 4096 + ntl_ * 1024);                    \
      dma16(Wl + o_, wbuf + w * 4096 + ntl_ * 1024 + 512);              \
    }                                                                   \
  }

  ISSUE_HALF(0, 0, 0, 0)
  ISSUE_HALF(0, 0, 0, 1)

  const bool z0 = (tloc == 0);
  for (int j = 0; j < 5; ++j) {
    f16x8 ah[4], al[4];
#pragma unroll
    for (int c = 0; c < 8; ++c) {
      const int kk = c >> 1, ntg = c & 1;
      if (ntg == 0) {
        // hoisted A fragments for this (j,kk): independent of nt
#pragma unroll
        for (int rt = 0; rt < 4; ++rt) {
          ah[rt] = *(const f16x8*)&xbuf[(rt * 16 + lo + j) * 264 + kk * 32 +
                                        quad * 8];
          al[rt] = *(const f16x8*)&xbuf[(rt * 16 + lo + j) * 264 + 128 +
                                        kk * 32 + quad * 8];
        }
        if (z0 && (lo + j < 4)) {
#pragma unroll
          for (int e = 0; e < 8; ++e) { ah[0][e] = (f16)0; al[0][e] = (f16)0; }
        }
      }
      // next chunk coordinates (pipeline crosses kk and j boundaries)
      const int nj = (c == 7) ? j + 1 : j;
      const int nkk = (c == 7) ? 0 : ((c + 1) >> 1);
      const int nntg = (c == 7) ? 0 : ((c + 1) & 1);
      const bool more = (c < 7) || (j < 4);

      wait_vm4();                 // half0(j,c) landed; 4+ stay in flight
#pragma unroll
      for (int ntl = 0; ntl < 2; ++ntl) {
        const int nt = ntg * 4 + ntl;
        const f16x8 bh = *(const f16x8*)&wbuf[w * 4096 + ntl * 1024 +
                                              quad * 128 + lo * 8];
        const f16x8 bl = *(const f16x8*)&wbuf[w * 4096 + ntl * 1024 + 512 +
                                              quad * 128 + lo * 8];
#pragma unroll
        for (int rt = 0; rt < 4; ++rt) {
          aq[rt][nt] = MFMA16(ah[rt], bh, aq[rt][nt]);
          aq[rt][nt] = MFMA16(ah[rt], bl, aq[rt][nt]);
          aq[rt][nt] = MFMA16(al[rt], bh, aq[rt][nt]);
        }
      }
      wait_lgkm0();               // half0 reads sampled before slot reuse
      if (more) ISSUE_HALF(nj, nkk, nntg, 0)

      if (c == 7) {               // last chunk of j: maybe nothing behind
        if (j == 4) wait_vm0(); else wait_vm4();
      } else {
        wait_vm4();               // half1(j,c) landed
      }
#pragma unroll
      for (int ntl = 2; ntl < 4; ++ntl) {
        const int nt = ntg * 4 + ntl;
        const f16x8 bh = *(const f16x8*)&wbuf[w * 4096 + ntl * 1024 +
                                              quad * 128 + lo * 8];
        const f16x8 bl = *(const f16x8*)&wbuf[w * 4096 + ntl * 1024 + 512 +
                                              quad * 128 + lo * 8];
#pragma unroll
        for (int rt = 0; rt < 4; ++rt) {
          aq[rt][nt] = MFMA16(ah[rt], bh, aq[rt][nt]);
          aq[rt][nt] = MFMA16(ah[rt], bl, aq[rt][nt]);
          aq[rt][nt] = MFMA16(al[rt], bh, aq[rt][nt]);
        }
      }
      wait_lgkm0();               // half1 reads sampled before slot reuse
      if (more) ISSUE_HALF(nj, nkk, nntg, 1)
    }
  }
#undef ISSUE_HALF

  const float SC = 0.29730177875068026f;  // 128^-0.25
#pragma unroll
  for (int nt = 0; nt < 8; ++nt) {
    const int o = o0 + nt * 16 + lo;
    const float vb = bias[o];
#pragma unroll
    for (int rt = 0; rt < 4; ++rt)
#pragma unroll
      for (int r = 0; r < 4; ++r) aq[rt][nt][r] = (aq[rt][nt][r] + vb) * SC;
  }

  if (!isK) {
    STAGE_QK(q3h, 0, (f16)aq[rt][nt][r])
    STAGE_QK(q3h, 1, (f16)aq[rt][nt][r])
    STAGE_QK(q3l, 0, (f16)(aq[rt][nt][r] - (float)(f16)aq[rt][nt][r]))
    STAGE_QK(q3l, 1, (f16)(aq[rt][nt][r] - (float)(f16)aq[rt][nt][r]))
  } else {
    STAGE_QK(k3h, 0, (f16)aq[rt][nt][r])
    STAGE_QK(k3h, 1, (f16)aq[rt][nt][r])
    STAGE_QK(k3l, 0, (f16)(aq[rt][nt][r] - (float)(f16)aq[rt][nt][r]))
    STAGE_QK(k3l, 1, (f16)(aq[rt][nt][r] - (float)(f16)aq[rt][nt][r]))
  }
}

// ---------------- K234: 32 Q-rows/block, Q staged once, continuous K -------
// (R17 version: best measured, ~207 us.) ALL 16 Q-frag slots staged once;
// K stream continuous across segments with counted vmcnt(2); half-1's first
// pair flies over the half-0 snapshot. Shared single V stream (4 MFMA per
// chunk, 2 per group). ev[2][2][16] lives across PV (modest scratch spill
// measured cheaper than recomputing exps - R18). LDS 66,560 B, aliased.
__global__ __launch_bounds__(512, 4) void k234_attn(
    const f16* __restrict__ q3h, const f16* __restrict__ q3l,
    const f16* __restrict__ k3h, const f16* __restrict__ k3l,
    const f16* __restrict__ v3T, f16* __restrict__ A) {
  __shared__ __align__(16) char smem[66560];
  float* const SbQ = (float*)smem;                 // 16 x 268 f32 (phase 1)
  f16* const PbufA = (f16*)smem;                   // grp0: 16 x 520 (phase 3)
  f16* const qlds = (f16*)(smem + 17152);          // 16 slots x 512 (phase 1)
  f16* const PbufB = (f16*)(smem + 17152);         // grp1: 16 x 520 (phase 3)
  f16* const kbuf = (f16*)(smem + 33792);          // 32768 B: 8w x 4 x 512
  const int tid = threadIdx.x;
  const int w = tid >> 6, lane = tid & 63;
  const int quad = lane >> 4, lo = lane & 15;
  const int qd = lane & 3, cit = lane >> 2;       // DMA lanes: [row][piece]
  const int qsw = qd ^ ((cit >> 1) & 3);          // bank-swizzled piece
  const int fro = (lo * 4 + (quad ^ ((lo >> 1) & 3))) * 8;  // fragment read
  // bijective XCD remap: 2048 blocks = 8 xcd * 8 m * 32 r0-blocks
  const int hid = blockIdx.y * 32 + blockIdx.x;
  const int m = (hid & 7) * 8 + ((hid >> 3) >> 5);
  const int r0 = ((hid >> 3) & 31) * 32;

  unsigned key[2][2][16];          // [grp][rr][j]
  unsigned kmn[2][2];
#pragma unroll
  for (int g = 0; g < 2; ++g)
#pragma unroll
    for (int rr = 0; rr < 2; ++rr) kmn[g][rr] = 0xFFFFFFFFu;

  // ---- stage ALL Q fragments once: slot = seg*4 + grp*2 + h ---------------
  {
#pragma unroll
    for (int s2 = 0; s2 < 2; ++s2) {
      const int sl = w * 2 + s2;
      const int seg = sl >> 2, grp_ = (sl >> 1) & 1, h_ = sl & 1;
      const f16* qsrc = (h_ ? q3l : q3h) +
          ((int64_t)m * 1024 + r0 + grp_ * 16 + lo) * 128 + seg * 32 +
          quad * 8;
      dma16(qsrc, qlds + sl * 512);
    }
    wait_vm0();                    // own 2 DMAs landed
    __syncthreads();               // all Q slots visible to all waves
  }

  // K chunk (HALF, C): rows (HALF*512 + (C&3)*128 + w*16 + ..), cols seg*32
#define KISS(HALF, C, PAIR)                                              \
  {                                                                      \
    const int64_t rowg =                                                 \
        (int64_t)(m * 1024 + (HALF) * 512 + ((C) & 3) * 128 + w * 16 +   \
                  cit) * 128 + ((C) >> 2) * 32 + qsw * 8;                \
    dma16(k3h + rowg, kbuf + (w * 4 + (PAIR) * 2) * 512);                \
    dma16(k3l + rowg, kbuf + (w * 4 + (PAIR) * 2 + 1) * 512);            \
  }

  // ---- phase 1: S = Q @ K^T, one continuous ping-pong stream --------------
  KISS(0, 0, 0)
  KISS(0, 1, 1)
#pragma unroll
  for (int half = 0; half < 2; ++half) {
    f32x4 acc[2][4];               // [grp][cc]
#pragma unroll
    for (int g = 0; g < 2; ++g)
#pragma unroll
      for (int i = 0; i < 4; ++i)
#pragma unroll
        for (int r = 0; r < 4; ++r) acc[g][i][r] = 0.f;

#pragma unroll
    for (int c = 0; c < 16; ++c) {
      const int g = half * 16 + c;
      if (g == 31) wait_vm0();     // last chunk of the block's K stream
      else wait_vm2();             // chunk g landed; next pair in flight
      const int pair = c & 1;      // == g & 1
      const int seg = c >> 2, cc = c & 3;
      const f16x8 qh0 = ldfrag(qlds + (seg * 4 + 0) * 512 + lane * 8);
      const f16x8 ql0 = ldfrag(qlds + (seg * 4 + 1) * 512 + lane * 8);
      const f16x8 qh1 = ldfrag(qlds + (seg * 4 + 2) * 512 + lane * 8);
      const f16x8 ql1 = ldfrag(qlds + (seg * 4 + 3) * 512 + lane * 8);
      const f16x8 bh = *(const f16x8*)(kbuf + (w * 4 + pair * 2) * 512 + fro);
      const f16x8 bl =
          *(const f16x8*)(kbuf + (w * 4 + pair * 2 + 1) * 512 + fro);
      acc[0][cc] = MFMA16(qh0, bh, acc[0][cc]);
      acc[0][cc] = MFMA16(qh0, bl, acc[0][cc]);
      acc[0][cc] = MFMA16(ql0, bh, acc[0][cc]);
      acc[1][cc] = MFMA16(qh1, bh, acc[1][cc]);
      acc[1][cc] = MFMA16(qh1, bl, acc[1][cc]);
      acc[1][cc] = MFMA16(ql1, bh, acc[1][cc]);
      wait_lgkm0();                // reads sampled before pair re-targeted
      const int gn = g + 2;
      if (gn < 32) KISS(gn >> 4, gn & 15, gn & 1)
    }

    // write S + snapshot keys, per (group, 256-col quarter); half-1's first
    // K pair is already in flight and rides over these barriers.
#pragma unroll
    for (int grp = 0; grp < 2; ++grp) {
#pragma unroll
      for (int q = 0; q < 2; ++q) {
#pragma unroll
        for (int c2 = 0; c2 < 2; ++c2)
#pragma unroll
          for (int r = 0; r < 4; ++r)
            SbQ[(quad * 4 + r) * 268 + c2 * 128 + w * 16 + lo] =
                acc[grp][q * 2 + c2][r];
        __syncthreads();   // cross-wave: snapshot reads other waves' columns
#pragma unroll
        for (int rr = 0; rr < 2; ++rr) {
          const float4 f4 =
              *(const float4*)(SbQ + (w * 2 + rr) * 268 + lane * 4);
          const float fe[4] = {f4.x, f4.y, f4.z, f4.w};
#pragma unroll
          for (int e = 0; e < 4; ++e) {
            const unsigned u = __builtin_bit_cast(unsigned, fe[e]);
            const unsigned k = (u & 0x80000000u) ? ~u : (u | 0x80000000u);
            key[grp][rr][half * 8 + q * 4 + e] = k;
            kmn[grp][rr] = min(kmn[grp][rr], k);
          }
        }
        __syncthreads();  // key reads done before next quarter overwrites
      }
    }
  }
#undef KISS

  // ---- pre-issue V kb0/kb1; latency hides under the radix ----------------
  const int64_t vrow = (int64_t)(m * 128 + w * 16 + cit) * 1024;
  const int nkbM = ((r0 + 16) >> 6) + 1;   // grp1 span >= grp0 span
#define VISSUE(KB, PAIR)                                                 \
  {                                                                      \
    dma16(v3T + vrow + (KB) * 64 + qsw * 8,                              \
          kbuf + (w * 4 + (PAIR) * 2) * 512);                            \
    dma16(v3T + vrow + (KB) * 64 + 32 + qsw * 8,                         \
          kbuf + (w * 4 + (PAIR) * 2 + 1) * 512);                       \
  }
  VISSUE(0, 0)
  if (nkbM > 1) VISSUE(1, 1)

  // ---- phase 2a: row-min reduce + exact top-64 radix (4 rows/wave) -------
#pragma unroll
  for (int off = 32; off; off >>= 1) {
#pragma unroll
    for (int g = 0; g < 2; ++g)
#pragma unroll
      for (int rr = 0; rr < 2; ++rr)
        kmn[g][rr] = min(kmn[g][rr],
                         (unsigned)__shfl_xor((int)kmn[g][rr], off));
  }
  unsigned th[2][2] = {{0u, 0u}, {0u, 0u}};
  {
    bool dn[2][2] = {{false, false}, {false, false}};
    for (int b = 31; b >= 0; --b) {
      bool all = true;
#pragma unroll
      for (int g = 0; g < 2; ++g)
#pragma unroll
        for (int rr = 0; rr < 2; ++rr) {
          if (!dn[g][rr]) {
            const unsigned c = th[g][rr] | (1u << b);
            int cnt = 0;
#pragma unroll
            for (int i = 0; i < 16; ++i)
              cnt += (int)__popcll(__ballot(key[g][rr][i] >= c));
            if (cnt >= 64) { th[g][rr] = c; if (cnt == 64) dn[g][rr] = true; }
          }
          all = all && dn[g][rr];
        }
      if (all) break;
    }
  }

  // ---- phase 2b: softmax weights for BOTH groups (keys -> ev in place) ---
  float ev[2][2][16];              // [grp][rr][j]
  float inv[2][2];
#pragma unroll
  for (int g = 0; g < 2; ++g)
#pragma unroll
    for (int rr = 0; rr < 2; ++rr) {
      const unsigned kth = th[g][rr];
      const unsigned kmv = kmn[g][rr];
      const int t2 = r0 + g * 16 + w * 2 + rr;
      const unsigned umn = (kmv & 0x80000000u) ? (kmv ^ 0x80000000u) : ~kmv;
      const float mn = __builtin_bit_cast(float, umn);   // exact row min
      const unsigned ukv = (kth & 0x80000000u) ? (kth ^ 0x80000000u) : ~kth;
      const float kv = __builtin_bit_cast(float, ukv);   // selection thresh
      float sum = 0.f;
#pragma unroll
      for (int j = 0; j < 16; ++j) {
        const int s = (j >> 2) * 256 + lane * 4 + (j & 3);
        const unsigned k = key[g][rr][j];
        const unsigned uu = (k & 0x80000000u) ? (k ^ 0x80000000u) : ~k;
        const float f = __builtin_bit_cast(float, uu);
        const float ww = (k >= kth) ? f : mn;
        const float x = (s <= t2) ? __expf(ww - kv) : 0.f;  // kv-stabilized
        ev[g][rr][j] = x;
        sum += x;
      }
      for (int off = 32; off; off >>= 1) sum += __shfl_xor(sum, off);
      inv[g][rr] = 1.0f / sum;
    }

  // ---- phase 3: ONE V stream, 4 MFMA per chunk (2 per group) -------------
  {
    const int nkb0h = nkbM < 8 ? nkbM : 8;     // half-0 span
    // write P half 0 for both groups (cols 0..511 = ev[..][0..7])
#pragma unroll
    for (int g = 0; g < 2; ++g) {
      f16* const pb = g ? PbufB : PbufA;
#pragma unroll
      for (int rr = 0; rr < 2; ++rr) {
        f16* prow = pb + (w * 2 + rr) * 520;
#pragma unroll
        for (int i2 = 0; i2 < 2; ++i2) {
          f16x4 pk;
#pragma unroll
          for (int e = 0; e < 4; ++e)
            pk[e] = (f16)(ev[g][rr][i2 * 4 + e] * inv[g][rr]);
          *(f16x4*)(prow + i2 * 256 + lane * 4) = pk;
        }
      }
    }
    __syncthreads();  // P half-0 visible to all waves

    f32x4 oaA0, oaA1, oaB0, oaB1;
#pragma unroll
    for (int r = 0; r < 4; ++r) {
      oaA0[r] = 0.f; oaA1[r] = 0.f; oaB0[r] = 0.f; oaB1[r] = 0.f;
    }
    for (int kb = 0; kb < nkb0h; ++kb) {
      if (kb + 1 < nkb0h) wait_vm2();  // kb landed; kb+1 stays in flight
      else wait_vm0();
      const int pair = kb & 1;
      {
        const f16x8 vf0 =
            *(const f16x8*)(kbuf + (w * 4 + pair * 2) * 512 + fro);
        const f16x8 vf1 =
            *(const f16x8*)(kbuf + (w * 4 + pair * 2 + 1) * 512 + fro);
        const f16x8 aA0 =
            *(const f16x8*)(PbufA + lo * 520 + kb * 64 + quad * 8);
        const f16x8 aA1 =
            *(const f16x8*)(PbufA + lo * 520 + kb * 64 + 32 + quad * 8);
        const f16x8 aB0 =
            *(const f16x8*)(PbufB + lo * 520 + kb * 64 + quad * 8);
        const f16x8 aB1 =
            *(const f16x8*)(PbufB + lo * 520 + kb * 64 + 32 + quad * 8);
        oaA0 = MFMA16(aA0, vf0, oaA0);
        oaA1 = MFMA16(aA1, vf1, oaA1);
        oaB0 = MFMA16(aB0, vf0, oaB0);
        oaB1 = MFMA16(aB1, vf1, oaB1);
      }
      wait_lgkm0();                    // reads sampled before slot reuse
      if (kb + 2 < nkb0h) VISSUE(kb + 2, pair)
    }

    if (nkbM > 8) {
      // pre-issue half-1 V (rides over the P rewrite)
      VISSUE(8, 0)
      if (nkbM > 9) VISSUE(9, 1)
      __syncthreads();  // PV half-0 af reads done before P rewrite
#pragma unroll
      for (int g = 0; g < 2; ++g) {
        f16* const pb = g ? PbufB : PbufA;
#pragma unroll
        for (int rr = 0; rr < 2; ++rr) {
          f16* prow = pb + (w * 2 + rr) * 520;
#pragma unroll
          for (int i2 = 0; i2 < 2; ++i2) {
            f16x4 pk;
#pragma unroll
            for (int e = 0; e < 4; ++e)
              pk[e] = (f16)(ev[g][rr][8 + i2 * 4 + e] * inv[g][rr]);
            *(f16x4*)(prow + i2 * 256 + lane * 4) = pk;
          }
        }
      }
      __syncthreads();  // P half-1 visible
      for (int kb = 8; kb < nkbM; ++kb) {
        if (kb + 1 < nkbM) wait_vm2();
        else wait_vm0();
        const int pair = kb & 1;
        {
          const f16x8 vf0 =
              *(const f16x8*)(kbuf + (w * 4 + pair * 2) * 512 + fro);
          const f16x8 vf1 =
              *(const f16x8*)(kbuf + (w * 4 + pair * 2 + 1) * 512 + fro);
          const f16x8 aA0 =
              *(const f16x8*)(PbufA + lo * 520 + (kb - 8) * 64 + quad * 8);
          const f16x8 aA1 =
              *(const f16x8*)(PbufA + lo * 520 + (kb - 8) * 64 + 32 + quad * 8);
          const f16x8 aB0 =
              *(const f16x8*)(PbufB + lo * 520 + (kb - 8) * 64 + quad * 8);
          const f16x8 aB1 =
              *(const f16x8*)(PbufB + lo * 520 + (kb - 8) * 64 + 32 + quad * 8);
          oaA0 = MFMA16(aA0, vf0, oaA0);
          oaA1 = MFMA16(aA1, vf1, oaA1);
          oaB0 = MFMA16(aB0, vf0, oaB0);
          oaB1 = MFMA16(aB1, vf1, oaB1);
        }
        wait_lgkm0();
        if (kb + 2 < nkbM) VISSUE(kb + 2, pair)
      }
    }

#pragma unroll
    for (int r = 0; r < 4; ++r) {
      A[((int64_t)m * 1024 + r0 + quad * 4 + r) * 128 + w * 16 + lo] =
          (f16)(oaA0[r] + oaA1[r]);
      A[((int64_t)m * 1024 + r0 + 16 + quad * 4 + r) * 128 + w * 16 + lo] =
          (f16)(oaB0[r] + oaB1[r]);
    }
  }
#undef VISSUE
}

// ---------------- K5: gather + output projection + bias --------------------
__global__ __launch_bounds__(256) void k5_proj(
    const f16* __restrict__ A, const f16* __restrict__ Wub,
    const float* __restrict__ bu, float* __restrict__ out) {
  const int w = threadIdx.x >> 6, lane = threadIdx.x & 63;
  const int quad = lane >> 4, lo = lane & 15;
  const int rt = w & 1, ch = w >> 1;
  const int r0 = blockIdx.x * 32 + rt * 16;  // row in [0,8192) = b*1024 + t2
  const int r = r0 + lo;
  const int bI = r >> 10, t2 = r & 1023;

  f32x4 acc[4];
#pragma unroll
  for (int i = 0; i < 4; ++i)
#pragma unroll
    for (int rr = 0; rr < 4; ++rr) acc[i][rr] = 0.f;

#pragma unroll 2
  for (int kk = 0; kk < 32; ++kk) {
    const int o = kk * 32 + quad * 8;  // feature index 0..1023
    const int j = o >> 7, kc = o & 127;
    f16x8 a = ldfrag(A + (((int64_t)(bI * 8 + j) * 1024 + t2) * 128 + kc));
    f16x8 wb[4];
#pragma unroll
    for (int nt = 0; nt < 4; ++nt)
      wb[nt] = ldfrag(Wub + (int64_t)(ch * 64 + nt * 16 + lo) * 1024 + o);
#pragma unroll
    for (int nt = 0; nt < 4; ++nt) acc[nt] = MFMA16(a, wb[nt], acc[nt]);
  }
#pragma unroll
  for (int nt = 0; nt < 4; ++nt) {
    const int col = ch * 64 + nt * 16 + lo;
    const float bias = bu[col];
#pragma unroll
    for (int rr = 0; rr < 4; ++rr) {
      const int row = r0 + quad * 4 + rr;
      out[(int64_t)row * 128 + col] = acc[nt][rr] + bias;
    }
  }
}

// ---------------- launcher --------------------------------------------------
extern "C" void kernel_launch(void* const* d_in, const int* in_sizes, int n_in,
                              void* d_out, int out_size, void* d_ws, size_t ws_size,
                              hipStream_t stream) {
  const float* x  = (const float*)d_in[0];
  const float* Wq = (const float*)d_in[1];
  const float* bq = (const float*)d_in[2];
  const float* Wk = (const float*)d_in[3];
  const float* bk = (const float*)d_in[4];
  const float* Wv = (const float*)d_in[5];
  const float* bv = (const float*)d_in[6];
  const float* Wu = (const float*)d_in[7];
  const float* bu = (const float*)d_in[8];
  float* out = (float*)d_out;

  char* ws = (char*)d_ws;
  f16* xh  = (f16*)ws;  ws += 2097152;
  f16* xl  = (f16*)ws;  ws += 2097152;
  f16* Wqh = (f16*)ws;  ws += 1310720;
  f16* Wql = (f16*)ws;  ws += 1310720;
  f16* Wkh = (f16*)ws;  ws += 1310720;
  f16* Wkl = (f16*)ws;  ws += 1310720;
  f16* Wvb = (f16*)ws;  ws += 262144;
  f16* Wub = (f16*)ws;  ws += 262144;
  f16* q3h = (f16*)ws;  ws += 16777216;           // 64*1024*128 fp16
  f16* q3l = (f16*)ws;  ws += 16777216;
  f16* k3h = (f16*)ws;  ws += 16777216;
  f16* k3l = (f16*)ws;  ws += 16777216;
  f16* v3T = (f16*)ws;  ws += 16777216;
  f16* A   = (f16*)ws;  ws += 16777216;           // total ~105.5 MB

  // K0: repack (exactly 2621440 threads = 10240 * 256)
  k0_prep<<<10240, 256, 0, stream>>>(x, Wq, Wk, Wv, Wu,
                                     xh, xl, Wqh, Wql, Wkh, Wkl, Wvb, Wub);

  // K1: convs + scramble; pipelined weight + V streams
  k1_conv<<<dim3(128, 2, 2), 256, 0, stream>>>(xh, xl, Wqh, Wql, Wkh, Wkl, Wvb,
                                               bq, bk, bv, q3h, q3l, k3h, k3l,
                                               v3T);

  // K234: R17 structure (Q staged once, continuous K, shared V)
  k234_attn<<<dim3(32, 64), 512, 0, stream>>>(q3h, q3l, k3h, k3l, v3T, A);

  // K5: projection (8192 rows / 32 per block)
  k5_proj<<<256, 256, 0, stream>>>(A, Wub, bu, out);

  (void)in_sizes; (void)n_in; (void)out_size; (void)ws_size;
}